// Round 1
// baseline (1078.709 us; speedup 1.0000x reference)
//
#include <hip/hip_runtime.h>

#define T_LEN 1024
#define B_SZ 4
#define EMB 1024
#define NH 16
#define HD 64
#define QKV_LD 3072   // row stride of qkv workspace

// ---------------------------------------------------------------------------
// GEMM: C[m][n] = sum_k A[m][k] * B[n][k] + bias[n]
// A: MxK row-major, B: NxK row-major (i.e. C = A * B^T), C: MxN row-major.
// Block tile 128x64, BK=16, 256 threads, 8x4 micro-tile per thread.
// ---------------------------------------------------------------------------
__global__ __launch_bounds__(256) void gemm_abt(
    const float* __restrict__ A, const float* __restrict__ B,
    const float* __restrict__ bias, float* __restrict__ C,
    int M, int N, int K)
{
    __shared__ float As[16][132];  // [k][m], +4 pad: transposed stores 2-way (free)
    __shared__ float Bs[16][68];   // [k][n]
    const int tid = threadIdx.x;
    const int tm = tid >> 4, tn = tid & 15;
    const int m0 = blockIdx.x * 128, n0 = blockIdx.y * 64;
    const int lrow = tid >> 2, kq = tid & 3;

    float acc[8][4];
#pragma unroll
    for (int i = 0; i < 8; ++i)
#pragma unroll
        for (int j = 0; j < 4; ++j) acc[i][j] = 0.0f;

    for (int k0 = 0; k0 < K; k0 += 16) {
#pragma unroll
        for (int hf = 0; hf < 2; ++hf) {
            const int r = lrow + hf * 64;
            const float4 v = *(const float4*)(A + (size_t)(m0 + r) * K + k0 + kq * 4);
            As[kq*4+0][r] = v.x; As[kq*4+1][r] = v.y;
            As[kq*4+2][r] = v.z; As[kq*4+3][r] = v.w;
        }
        {
            const float4 v = *(const float4*)(B + (size_t)(n0 + lrow) * K + k0 + kq * 4);
            Bs[kq*4+0][lrow] = v.x; Bs[kq*4+1][lrow] = v.y;
            Bs[kq*4+2][lrow] = v.z; Bs[kq*4+3][lrow] = v.w;
        }
        __syncthreads();
#pragma unroll
        for (int k = 0; k < 16; ++k) {
            const float4 a0 = *(const float4*)&As[k][tm*8];
            const float4 a1 = *(const float4*)&As[k][tm*8+4];
            const float4 bv = *(const float4*)&Bs[k][tn*4];
            const float av[8] = {a0.x,a0.y,a0.z,a0.w,a1.x,a1.y,a1.z,a1.w};
            const float bw[4] = {bv.x,bv.y,bv.z,bv.w};
#pragma unroll
            for (int i = 0; i < 8; ++i)
#pragma unroll
                for (int j = 0; j < 4; ++j)
                    acc[i][j] = fmaf(av[i], bw[j], acc[i][j]);
        }
        __syncthreads();
    }
    const float4 bb = *(const float4*)(bias + n0 + tn*4);
#pragma unroll
    for (int i = 0; i < 8; ++i) {
        float4 o;
        o.x = acc[i][0] + bb.x;
        o.y = acc[i][1] + bb.y;
        o.z = acc[i][2] + bb.z;
        o.w = acc[i][3] + bb.w;
        *(float4*)(C + (size_t)(m0 + tm*8 + i) * N + n0 + tn*4) = o;
    }
}

// ---------------------------------------------------------------------------
// Fused flash-style attention. One block = 64 q-rows of one (b,h).
// qkv layout: [t*B_SZ + b][3*EMB]; q at 0, k at EMB, v at 2*EMB; head slice h*HD.
// Online softmax with running m,l per row; O accumulated in registers (4x4/thread).
// LDS: Qs [d][r] (transposed), KP union: K-phase [d][c] / P-phase [c][r], Vs [c][d].
// 3 x 64x68 f32 = 52 KB -> 2 blocks/CU.
// ---------------------------------------------------------------------------
__global__ __launch_bounds__(256) void attn_fused(
    const float* __restrict__ qkv, const int* __restrict__ kpm,
    const float* __restrict__ attn_mask, const float* __restrict__ attn_bias,
    float* __restrict__ ctx)
{
    __shared__ float Qs[64 * 68];
    __shared__ float KP[64 * 68];
    __shared__ float Vs[64 * 68];

    const int tid = threadIdx.x;
    const int tx = tid & 15, ty = tid >> 4;   // thread owns rows 4ty..+3, cols 4tx..+3
    const int q0 = blockIdx.x * 64;
    const int bh = blockIdx.y;
    const int b = bh >> 4, hh = bh & 15;      // bh = b*NH + h
    const size_t head_off = (size_t)b * QKV_LD + hh * HD;

    // stage Q tile, scaled, transposed to [d][r]
#pragma unroll
    for (int j = 0; j < 4; ++j) {
        const int f = tid + 256 * j;
        const int r = f >> 4, d4 = f & 15;
        const float4 v = *(const float4*)(qkv + (size_t)(q0 + r) * B_SZ * QKV_LD + head_off + d4 * 4);
        Qs[(d4*4+0)*68 + r] = v.x * 0.125f;
        Qs[(d4*4+1)*68 + r] = v.y * 0.125f;
        Qs[(d4*4+2)*68 + r] = v.z * 0.125f;
        Qs[(d4*4+3)*68 + r] = v.w * 0.125f;
    }

    float m_i[4], l_i[4], O[4][4];
#pragma unroll
    for (int i = 0; i < 4; ++i) {
        m_i[i] = -1e30f; l_i[i] = 0.0f;
#pragma unroll
        for (int j = 0; j < 4; ++j) O[i][j] = 0.0f;
    }

    for (int s0 = 0; s0 < T_LEN; s0 += 64) {
        __syncthreads();  // prior PV reads of KP/Vs done (also covers Qs staging, 1st iter)
        // stage K (transposed [d][c]) and V (natural [c][d])
#pragma unroll
        for (int j = 0; j < 4; ++j) {
            const int f = tid + 256 * j;
            const int c = f >> 4, d4 = f & 15;
            const float* kptr = qkv + (size_t)(s0 + c) * B_SZ * QKV_LD + head_off + EMB + d4 * 4;
            const float4 kv = *(const float4*)kptr;
            KP[(d4*4+0)*68 + c] = kv.x;
            KP[(d4*4+1)*68 + c] = kv.y;
            KP[(d4*4+2)*68 + c] = kv.z;
            KP[(d4*4+3)*68 + c] = kv.w;
            const float4 vv = *(const float4*)(kptr + EMB);
            *(float4*)&Vs[c*68 + d4*4] = vv;
        }
        __syncthreads();

        // S = Q K^T (4x4 per thread)
        float s[4][4];
#pragma unroll
        for (int i = 0; i < 4; ++i)
#pragma unroll
            for (int j = 0; j < 4; ++j) s[i][j] = 0.0f;
#pragma unroll 8
        for (int d = 0; d < 64; ++d) {
            const float4 qv = *(const float4*)&Qs[d*68 + ty*4];
            const float4 kv = *(const float4*)&KP[d*68 + tx*4];
            const float qa[4] = {qv.x,qv.y,qv.z,qv.w};
            const float ka[4] = {kv.x,kv.y,kv.z,kv.w};
#pragma unroll
            for (int i = 0; i < 4; ++i)
#pragma unroll
                for (int j = 0; j < 4; ++j)
                    s[i][j] = fmaf(qa[i], ka[j], s[i][j]);
        }

        // + attn_mask + attn_bias, key-padding -> -1e30
        const int4 kp = *(const int4*)(kpm + b * T_LEN + s0 + tx*4);
#pragma unroll
        for (int i = 0; i < 4; ++i) {
            const int t = q0 + ty*4 + i;
            const float4 mm = *(const float4*)(attn_mask + (size_t)t * T_LEN + s0 + tx*4);
            const float4 bb = *(const float4*)(attn_bias + ((size_t)bh * T_LEN + t) * T_LEN + s0 + tx*4);
            s[i][0] = kp.x ? -1e30f : s[i][0] + mm.x + bb.x;
            s[i][1] = kp.y ? -1e30f : s[i][1] + mm.y + bb.y;
            s[i][2] = kp.z ? -1e30f : s[i][2] + mm.z + bb.z;
            s[i][3] = kp.w ? -1e30f : s[i][3] + mm.w + bb.w;
        }

        __syncthreads();  // everyone done reading K from KP -> safe to overwrite with P

        // online softmax; write P transposed [c][r] into KP
#pragma unroll
        for (int i = 0; i < 4; ++i) {
            float rm = fmaxf(fmaxf(s[i][0], s[i][1]), fmaxf(s[i][2], s[i][3]));
            rm = fmaxf(rm, __shfl_xor(rm, 1, 16));
            rm = fmaxf(rm, __shfl_xor(rm, 2, 16));
            rm = fmaxf(rm, __shfl_xor(rm, 4, 16));
            rm = fmaxf(rm, __shfl_xor(rm, 8, 16));
            const float mn = fmaxf(m_i[i], rm);
            const float alpha = __expf(m_i[i] - mn);
            m_i[i] = mn;
            float p[4];
            float rs = 0.0f;
#pragma unroll
            for (int j = 0; j < 4; ++j) {
                p[j] = __expf(s[i][j] - mn);
                rs += p[j];
            }
            rs += __shfl_xor(rs, 1, 16);
            rs += __shfl_xor(rs, 2, 16);
            rs += __shfl_xor(rs, 4, 16);
            rs += __shfl_xor(rs, 8, 16);
            l_i[i] = l_i[i] * alpha + rs;
#pragma unroll
            for (int j = 0; j < 4; ++j) {
                O[i][j] *= alpha;
                KP[(tx*4+j)*68 + ty*4 + i] = p[j];
            }
        }
        __syncthreads();  // P visible to all

        // O += P V
#pragma unroll 8
        for (int c = 0; c < 64; ++c) {
            const float4 pv = *(const float4*)&KP[c*68 + ty*4];
            const float4 vv = *(const float4*)&Vs[c*68 + tx*4];
            const float pa[4] = {pv.x,pv.y,pv.z,pv.w};
            const float va[4] = {vv.x,vv.y,vv.z,vv.w};
#pragma unroll
            for (int i = 0; i < 4; ++i)
#pragma unroll
                for (int j = 0; j < 4; ++j)
                    O[i][j] = fmaf(pa[i], va[j], O[i][j]);
        }
    }

    // epilogue: ctx[t][b][h*HD + d] = O / l
#pragma unroll
    for (int i = 0; i < 4; ++i) {
        const float inv = 1.0f / l_i[i];
        const int t = q0 + ty*4 + i;
        float4 o;
        o.x = O[i][0] * inv; o.y = O[i][1] * inv;
        o.z = O[i][2] * inv; o.w = O[i][3] * inv;
        *(float4*)(ctx + (size_t)t * B_SZ * EMB + (size_t)b * EMB + hh * HD + tx * 4) = o;
    }
}

// ---------------------------------------------------------------------------
extern "C" void kernel_launch(void* const* d_in, const int* in_sizes, int n_in,
                              void* d_out, int out_size, void* d_ws, size_t ws_size,
                              hipStream_t stream)
{
    const float* query     = (const float*)d_in[0];
    const int*   kpm       = (const int*)  d_in[1];
    const float* attn_mask = (const float*)d_in[2];
    const float* attn_bias = (const float*)d_in[3];
    const float* W_in      = (const float*)d_in[4];
    const float* b_in      = (const float*)d_in[5];
    const float* W_out     = (const float*)d_in[6];
    const float* b_out     = (const float*)d_in[7];
    float* out = (float*)d_out;

    float* qkv = (float*)d_ws;                                  // 4096 x 3072 f32 (48 MB)
    float* ctx = qkv + (size_t)T_LEN * B_SZ * QKV_LD;           // 4096 x 1024 f32 (16 MB)

    // K1: qkv = query * W_in^T + b_in   (M=4096, N=3072, K=1024)
    dim3 g1(4096 / 128, 3072 / 64);
    gemm_abt<<<g1, 256, 0, stream>>>(query, W_in, b_in, qkv, 4096, 3072, 1024);

    // K2: fused attention -> ctx (t,b,e layout)
    dim3 g2(T_LEN / 64, B_SZ * NH);
    attn_fused<<<g2, 256, 0, stream>>>(qkv, kpm, attn_mask, attn_bias, ctx);

    // K3: out = ctx * W_out^T + b_out   (M=4096, N=1024, K=1024)
    dim3 g3(4096 / 128, 1024 / 64);
    gemm_abt<<<g3, 256, 0, stream>>>(ctx, W_out, b_out, out, 4096, 1024, 1024);
}

// Round 2
// 606.093 us; speedup vs baseline: 1.7798x; 1.7798x over previous
//
#include <hip/hip_runtime.h>

#define T_LEN 1024
#define B_SZ 4
#define EMB 1024
#define NH 16
#define HD 64
#define QKV_LD 3072   // row stride of qkv workspace (halves)

typedef _Float16 f16;
typedef __attribute__((ext_vector_type(8))) _Float16 f16x8;
typedef __attribute__((ext_vector_type(4))) _Float16 f16x4;
typedef __attribute__((ext_vector_type(4))) float f32x4;

// ---------------------------------------------------------------------------
// fp32 -> fp16 conversion, float4-vectorized
// ---------------------------------------------------------------------------
__global__ __launch_bounds__(256) void cvt_f32_to_f16(
    const float* __restrict__ in, f16* __restrict__ out, int n4)
{
    int i = blockIdx.x * 256 + threadIdx.x;
    if (i < n4) {
        float4 v = ((const float4*)in)[i];
        f16x4 h = { (f16)v.x, (f16)v.y, (f16)v.z, (f16)v.w };
        ((f16x4*)out)[i] = h;
    }
}

// ---------------------------------------------------------------------------
// f16 MFMA GEMM: C[m][n] = sum_k A[m][k]*B[n][k] + bias[n]  (C = A*B^T)
// A: MxK f16 row-major, B: NxK f16 row-major. Block tile 128x128, BK=32,
// 256 thr = 4 waves, each wave owns 64x64 via 4x4 tiles of 16x16x32 MFMA.
// LDS stride 40 halves -> max 2-way bank aliasing (free).
// OUT_HALF: write f16 (intermediate) else f32.
// ---------------------------------------------------------------------------
template<bool OUT_HALF>
__global__ __launch_bounds__(256) void gemm_f16(
    const f16* __restrict__ A, const f16* __restrict__ B,
    const float* __restrict__ bias, void* __restrict__ Cout,
    int M, int N, int K)
{
    const int LDT = 40;
    __shared__ f16 As[128 * 40];
    __shared__ f16 Bs[128 * 40];
    const int tid = threadIdx.x;
    const int wv = tid >> 6;
    const int lane = tid & 63;
    const int lq = lane & 15, quad = lane >> 4;
    const int m0 = blockIdx.x * 128, n0 = blockIdx.y * 128;
    const int wm = (wv >> 1) * 64, wn = (wv & 1) * 64;
    const int srow = tid >> 1, soff = (tid & 1) * 16;

    f32x4 acc[4][4];
#pragma unroll
    for (int i = 0; i < 4; ++i)
#pragma unroll
        for (int j = 0; j < 4; ++j) acc[i][j] = (f32x4){0.f, 0.f, 0.f, 0.f};

    const f16* ag = A + (size_t)(m0 + srow) * K + soff;
    const f16* bg = B + (size_t)(n0 + srow) * K + soff;

    for (int k0 = 0; k0 < K; k0 += 32) {
        const f16x8 a0 = *(const f16x8*)(ag + k0);
        const f16x8 a1 = *(const f16x8*)(ag + k0 + 8);
        const f16x8 b0 = *(const f16x8*)(bg + k0);
        const f16x8 b1 = *(const f16x8*)(bg + k0 + 8);
        *(f16x8*)&As[srow * LDT + soff]     = a0;
        *(f16x8*)&As[srow * LDT + soff + 8] = a1;
        *(f16x8*)&Bs[srow * LDT + soff]     = b0;
        *(f16x8*)&Bs[srow * LDT + soff + 8] = b1;
        __syncthreads();
        f16x8 af[4], bf[4];
#pragma unroll
        for (int t = 0; t < 4; ++t) {
            af[t] = *(const f16x8*)&As[(wm + t * 16 + lq) * LDT + quad * 8];
            bf[t] = *(const f16x8*)&Bs[(wn + t * 16 + lq) * LDT + quad * 8];
        }
#pragma unroll
        for (int mt = 0; mt < 4; ++mt)
#pragma unroll
            for (int nt = 0; nt < 4; ++nt)
                acc[mt][nt] = __builtin_amdgcn_mfma_f32_16x16x32_f16(
                    af[mt], bf[nt], acc[mt][nt], 0, 0, 0);
        __syncthreads();
    }

    // epilogue: C/D layout col = lane&15, row = quad*4 + reg
#pragma unroll
    for (int nt = 0; nt < 4; ++nt) {
        const int col = n0 + wn + nt * 16 + lq;
        const float bb = bias[col];
#pragma unroll
        for (int mt = 0; mt < 4; ++mt) {
#pragma unroll
            for (int r = 0; r < 4; ++r) {
                const int row = m0 + wm + mt * 16 + quad * 4 + r;
                const float val = acc[mt][nt][r] + bb;
                if (OUT_HALF)
                    ((f16*)Cout)[(size_t)row * N + col] = (f16)val;
                else
                    ((float*)Cout)[(size_t)row * N + col] = val;
            }
        }
    }
}

// ---------------------------------------------------------------------------
// Fused flash attention, f16 MFMA. Block = 64 q-rows of one (b,h), 4 waves.
// Wave w owns q-row band [16w,16w+16). Per 64-key tile:
//   S band = Q_band K^T (MFMA, 2 k-steps x 4 n-tiles)
//   fp32: *0.125 + mask + bias, kpm -> -1e30, online softmax
//   P (f16) -> LDS (C-layout -> A-layout transform), O += P V (MFMA)
// Qs/Ks natural [row][d], Vs transposed [d][s], stride 72 halves.
// ---------------------------------------------------------------------------
__global__ __launch_bounds__(256) void attn_f16(
    const f16* __restrict__ qkv, const int* __restrict__ kpm,
    const float* __restrict__ attn_mask, const float* __restrict__ attn_bias,
    f16* __restrict__ ctx)
{
    const int LD = 72;
    __shared__ f16 Qs[64 * 72];
    __shared__ f16 Ks[64 * 72];
    __shared__ f16 Vs[64 * 72];
    __shared__ f16 Ps[64 * 72];

    const int tid = threadIdx.x;
    const int wv = tid >> 6;
    const int lane = tid & 63;
    const int lq = lane & 15, quad = lane >> 4;
    const int q0 = blockIdx.x * 64;
    const int bh = blockIdx.y;
    const int b = bh >> 4, hh = bh & 15;
    const size_t base = (size_t)b * QKV_LD + hh * HD;
    const int sr = tid >> 2, so = (tid & 3) * 16;

    // stage Q band (natural [r][d])
    {
        const f16* qg = qkv + (size_t)(q0 + sr) * (B_SZ * QKV_LD) + base + so;
        *(f16x8*)&Qs[sr * LD + so]     = *(const f16x8*)qg;
        *(f16x8*)&Qs[sr * LD + so + 8] = *(const f16x8*)(qg + 8);
    }

    float m_i[4], l_i[4];
    f32x4 O[4];
#pragma unroll
    for (int r = 0; r < 4; ++r) { m_i[r] = -1e30f; l_i[r] = 0.0f; }
#pragma unroll
    for (int dt = 0; dt < 4; ++dt) O[dt] = (f32x4){0.f, 0.f, 0.f, 0.f};

    for (int s0 = 0; s0 < T_LEN; s0 += 64) {
        __syncthreads();  // prev PV done reading Ks/Vs/Ps (1st iter: Qs staged)
        // stage K natural [s][d]
        {
            const f16* kg = qkv + (size_t)(s0 + sr) * (B_SZ * QKV_LD) + base + EMB + so;
            *(f16x8*)&Ks[sr * LD + so]     = *(const f16x8*)kg;
            *(f16x8*)&Ks[sr * LD + so + 8] = *(const f16x8*)(kg + 8);
        }
        // stage V transposed [d][s]: lane covers s=lane, wave covers d-range
        {
            const f16* vg = qkv + (size_t)(s0 + lane) * (B_SZ * QKV_LD) + base + 2 * EMB + wv * 16;
            const f16x8 v0 = *(const f16x8*)vg;
            const f16x8 v1 = *(const f16x8*)(vg + 8);
#pragma unroll
            for (int j = 0; j < 8; ++j) Vs[(wv * 16 + j) * LD + lane] = v0[j];
#pragma unroll
            for (int j = 0; j < 8; ++j) Vs[(wv * 16 + 8 + j) * LD + lane] = v1[j];
        }
        __syncthreads();

        // S band = Q K^T
        f32x4 sacc[4];
#pragma unroll
        for (int nt = 0; nt < 4; ++nt) sacc[nt] = (f32x4){0.f, 0.f, 0.f, 0.f};
#pragma unroll
        for (int ks = 0; ks < 2; ++ks) {
            const f16x8 aq = *(const f16x8*)&Qs[(wv * 16 + lq) * LD + ks * 32 + quad * 8];
#pragma unroll
            for (int nt = 0; nt < 4; ++nt) {
                const f16x8 bk = *(const f16x8*)&Ks[(nt * 16 + lq) * LD + ks * 32 + quad * 8];
                sacc[nt] = __builtin_amdgcn_mfma_f32_16x16x32_f16(aq, bk, sacc[nt], 0, 0, 0);
            }
        }

        // scale + mask + bias + key-padding
        int kp[4];
#pragma unroll
        for (int nt = 0; nt < 4; ++nt) kp[nt] = kpm[b * T_LEN + s0 + nt * 16 + lq];
        float sv[4][4];
#pragma unroll
        for (int r = 0; r < 4; ++r) {
            const int t = q0 + wv * 16 + quad * 4 + r;
            const float* mrow = attn_mask + (size_t)t * T_LEN + s0;
            const float* brow = attn_bias + ((size_t)bh * T_LEN + t) * T_LEN + s0;
#pragma unroll
            for (int nt = 0; nt < 4; ++nt) {
                const float x = sacc[nt][r] * 0.125f + mrow[nt * 16 + lq] + brow[nt * 16 + lq];
                sv[r][nt] = kp[nt] ? -1e30f : x;
            }
        }

        // online softmax per row (row = quad*4+r, 16 cols spread over lq + 4 nt)
#pragma unroll
        for (int r = 0; r < 4; ++r) {
            float rm = fmaxf(fmaxf(sv[r][0], sv[r][1]), fmaxf(sv[r][2], sv[r][3]));
            rm = fmaxf(rm, __shfl_xor(rm, 1, 16));
            rm = fmaxf(rm, __shfl_xor(rm, 2, 16));
            rm = fmaxf(rm, __shfl_xor(rm, 4, 16));
            rm = fmaxf(rm, __shfl_xor(rm, 8, 16));
            const float mn = fmaxf(m_i[r], rm);
            const float alpha = __expf(m_i[r] - mn);
            m_i[r] = mn;
            float rs = 0.0f;
#pragma unroll
            for (int nt = 0; nt < 4; ++nt) {
                const float p = __expf(sv[r][nt] - mn);
                rs += p;
                Ps[(wv * 16 + quad * 4 + r) * LD + nt * 16 + lq] = (f16)p;
            }
            rs += __shfl_xor(rs, 1, 16);
            rs += __shfl_xor(rs, 2, 16);
            rs += __shfl_xor(rs, 4, 16);
            rs += __shfl_xor(rs, 8, 16);
            l_i[r] = l_i[r] * alpha + rs;
#pragma unroll
            for (int dt = 0; dt < 4; ++dt) O[dt][r] *= alpha;
        }
        __syncthreads();  // Ps visible

        // O band += P V
#pragma unroll
        for (int ks = 0; ks < 2; ++ks) {
            const f16x8 ap = *(const f16x8*)&Ps[(wv * 16 + lq) * LD + ks * 32 + quad * 8];
#pragma unroll
            for (int dt = 0; dt < 4; ++dt) {
                const f16x8 bv = *(const f16x8*)&Vs[(dt * 16 + lq) * LD + ks * 32 + quad * 8];
                O[dt] = __builtin_amdgcn_mfma_f32_16x16x32_f16(ap, bv, O[dt], 0, 0, 0);
            }
        }
    }

    // epilogue: ctx[t][b][hh*64 + d] f16
#pragma unroll
    for (int r = 0; r < 4; ++r) {
        const float inv = 1.0f / l_i[r];
        const int t = q0 + wv * 16 + quad * 4 + r;
#pragma unroll
        for (int dt = 0; dt < 4; ++dt) {
            const float val = O[dt][r] * inv;
            ctx[((size_t)t * B_SZ + b) * EMB + hh * HD + dt * 16 + lq] = (f16)val;
        }
    }
}

// ---------------------------------------------------------------------------
extern "C" void kernel_launch(void* const* d_in, const int* in_sizes, int n_in,
                              void* d_out, int out_size, void* d_ws, size_t ws_size,
                              hipStream_t stream)
{
    const float* query     = (const float*)d_in[0];
    const int*   kpm       = (const int*)  d_in[1];
    const float* attn_mask = (const float*)d_in[2];
    const float* attn_bias = (const float*)d_in[3];
    const float* W_in      = (const float*)d_in[4];
    const float* b_in      = (const float*)d_in[5];
    const float* W_out     = (const float*)d_in[6];
    const float* b_out     = (const float*)d_in[7];
    float* out = (float*)d_out;

    // workspace layout (f16)
    f16* q16    = (f16*)d_ws;                                   //  4096x1024
    f16* win16  = q16   + (size_t)4096 * 1024;                  //  3072x1024
    f16* wout16 = win16 + (size_t)3072 * 1024;                  //  1024x1024
    f16* qkv16  = wout16 + (size_t)1024 * 1024;                 //  4096x3072
    f16* ctx16  = qkv16 + (size_t)4096 * 3072;                  //  4096x1024
    // total 25.2M halves = 50.4 MB

    cvt_f32_to_f16<<<4096 * 1024 / 1024, 256, 0, stream>>>(query, q16,   4096 * 1024 / 4);
    cvt_f32_to_f16<<<3072 * 1024 / 1024, 256, 0, stream>>>(W_in,  win16, 3072 * 1024 / 4);
    cvt_f32_to_f16<<<1024 * 1024 / 1024, 256, 0, stream>>>(W_out, wout16,1024 * 1024 / 4);

    // K1: qkv16 = q16 * win16^T + b_in   (M=4096, N=3072, K=1024)
    dim3 g1(4096 / 128, 3072 / 128);
    gemm_f16<true><<<g1, 256, 0, stream>>>(q16, win16, b_in, qkv16, 4096, 3072, 1024);

    // K2: fused attention -> ctx16
    dim3 g2(T_LEN / 64, B_SZ * NH);
    attn_f16<<<g2, 256, 0, stream>>>(qkv16, kpm, attn_mask, attn_bias, ctx16);

    // K3: out = ctx16 * wout16^T + b_out (M=4096, N=1024, K=1024)
    dim3 g3(4096 / 128, 1024 / 128);
    gemm_f16<false><<<g3, 256, 0, stream>>>(ctx16, wout16, b_out, out, 4096, 1024, 1024);
}

// Round 3
// 591.177 us; speedup vs baseline: 1.8247x; 1.0252x over previous
//
#include <hip/hip_runtime.h>

#define T_LEN 1024
#define B_SZ 4
#define EMB 1024
#define NH 16
#define HD 64

typedef _Float16 f16;
typedef __attribute__((ext_vector_type(8))) _Float16 f16x8;
typedef __attribute__((ext_vector_type(4))) _Float16 f16x4;
typedef __attribute__((ext_vector_type(4))) float f32x4;

// async global->LDS, 16B per lane. LDS dest must be wave-uniform base + lane*16.
__device__ __forceinline__ void gload16(const f16* g, f16* l) {
    __builtin_amdgcn_global_load_lds(
        (const __attribute__((address_space(1))) void*)g,
        (__attribute__((address_space(3))) void*)l, 16, 0, 0);
}

// ---------------------------------------------------------------------------
__global__ __launch_bounds__(256) void cvt_f32_to_f16(
    const float* __restrict__ in, f16* __restrict__ out, int n4)
{
    int i = blockIdx.x * 256 + threadIdx.x;
    if (i < n4) {
        float4 v = ((const float4*)in)[i];
        f16x4 h = { (f16)v.x, (f16)v.y, (f16)v.z, (f16)v.w };
        ((f16x4*)out)[i] = h;
    }
}

// ---------------------------------------------------------------------------
// f16 MFMA GEMM, m97 structure: C = A*B^T + bias. 128x128 tile, BK=32,
// global_load_lds width-16 staging into unpadded [128][32] LDS.
// MODE 0: write f32 natural [M][N].  MODE 2: scatter f16 into per-head
// Qh[bh][t][d] / Kh[bh][s][d] / Vth[bh][d][t]  (N=3072 = q|k|v sections).
// ---------------------------------------------------------------------------
template<int MODE>
__global__ __launch_bounds__(256) void gemm_f16_v2(
    const f16* __restrict__ A, const f16* __restrict__ B,
    const float* __restrict__ bias, float* __restrict__ outF,
    f16* __restrict__ Qh, f16* __restrict__ Kh, f16* __restrict__ Vth,
    int M, int N, int K)
{
    __shared__ f16 As[128 * 32];
    __shared__ f16 Bs[128 * 32];
    const int tid = threadIdx.x;
    const int wv = tid >> 6, lane = tid & 63;
    const int lq = lane & 15, quad = lane >> 4;
    const int m0 = blockIdx.x * 128, n0 = blockIdx.y * 128;
    const int wm = (wv >> 1) * 64, wn = (wv & 1) * 64;

    // staging segment map: seg s -> row s>>2, k-chunk (s&3)*8
    const int s1 = tid, s2 = 256 + tid;
    const f16* a1 = A + (size_t)(m0 + (s1 >> 2)) * K + (s1 & 3) * 8;
    const f16* a2 = A + (size_t)(m0 + (s2 >> 2)) * K + (s2 & 3) * 8;
    const f16* b1 = B + (size_t)(n0 + (s1 >> 2)) * K + (s1 & 3) * 8;
    const f16* b2 = B + (size_t)(n0 + (s2 >> 2)) * K + (s2 & 3) * 8;
    f16* lA1 = As + s1 * 8; f16* lA2 = As + s2 * 8;
    f16* lB1 = Bs + s1 * 8; f16* lB2 = Bs + s2 * 8;

    f32x4 acc[4][4];
#pragma unroll
    for (int i = 0; i < 4; ++i)
#pragma unroll
        for (int j = 0; j < 4; ++j) acc[i][j] = (f32x4){0.f, 0.f, 0.f, 0.f};

    for (int k0 = 0; k0 < K; k0 += 32) {
        __syncthreads();          // previous frag reads done
        gload16(a1 + k0, lA1);
        gload16(a2 + k0, lA2);
        gload16(b1 + k0, lB1);
        gload16(b2 + k0, lB2);
        __syncthreads();          // staging visible (vmcnt drain)
        f16x8 af[4], bf[4];
#pragma unroll
        for (int t = 0; t < 4; ++t) {
            af[t] = *(const f16x8*)&As[(wm + t * 16 + lq) * 32 + quad * 8];
            bf[t] = *(const f16x8*)&Bs[(wn + t * 16 + lq) * 32 + quad * 8];
        }
#pragma unroll
        for (int mt = 0; mt < 4; ++mt)
#pragma unroll
            for (int nt = 0; nt < 4; ++nt)
                acc[mt][nt] = __builtin_amdgcn_mfma_f32_16x16x32_f16(
                    af[mt], bf[nt], acc[mt][nt], 0, 0, 0);
    }

    // epilogue: C/D layout col = lane&15 (n), row = quad*4+r (m)
#pragma unroll
    for (int nt = 0; nt < 4; ++nt) {
        const int col = n0 + wn + nt * 16 + lq;
        const float bb = bias[col];
        if (MODE == 0) {
#pragma unroll
            for (int mt = 0; mt < 4; ++mt)
#pragma unroll
                for (int r = 0; r < 4; ++r) {
                    const int row = m0 + wm + mt * 16 + quad * 4 + r;
                    outF[(size_t)row * N + col] = acc[mt][nt][r] + bb;
                }
        } else {
            const int sec = col >> 10, cc = col & 1023;
            const int h = cc >> 6, d = cc & 63;
#pragma unroll
            for (int mt = 0; mt < 4; ++mt)
#pragma unroll
                for (int r = 0; r < 4; ++r) {
                    const int row = m0 + wm + mt * 16 + quad * 4 + r;
                    const int t = row >> 2, b = row & 3;
                    const int bh = b * NH + h;
                    const f16 v = (f16)(acc[mt][nt][r] + bb);
                    if (sec == 0)      Qh[(size_t)bh * 65536 + t * 64 + d] = v;
                    else if (sec == 1) Kh[(size_t)bh * 65536 + t * 64 + d] = v;
                    else               Vth[(size_t)bh * 65536 + d * 1024 + t] = v;
                }
        }
    }
}

// ---------------------------------------------------------------------------
// Fused flash attention v2. Block = 64 q-rows of one bh, 4 waves, barrier-free.
// Computes S^T per tile: A=K (m=s), B=Q (n=t) -> C col = q-row, row = s.
// All fragments loaded directly from global per-head buffers (L2-resident).
// LDS only for the per-wave-private P (C-layout -> A-layout) round trip.
// ---------------------------------------------------------------------------
__global__ __launch_bounds__(256) void attn_v2(
    const f16* __restrict__ Qh, const f16* __restrict__ Kh,
    const f16* __restrict__ Vth, const int* __restrict__ kpm,
    const float* __restrict__ attn_mask, const float* __restrict__ attn_bias,
    f16* __restrict__ ctx)
{
    const int LDP = 72;
    __shared__ f16 Ps[4 * 16 * LDP];   // per-wave-private 16 x 64 P bands

    const int tid = threadIdx.x;
    const int wv = tid >> 6, lane = tid & 63;
    const int lq = lane & 15, quad = lane >> 4;
    const int q0 = blockIdx.x * 64;
    const int bh = blockIdx.y;
    const int b = bh >> 4, hh = bh & 15;

    const f16* Qb = Qh + (size_t)bh * 65536;
    const f16* Kb = Kh + (size_t)bh * 65536;
    const f16* Vb = Vth + (size_t)bh * 65536;
    f16* Pw = Ps + wv * 16 * LDP;

    const int t = q0 + wv * 16 + lq;   // this thread's softmax q-row
    const float* mrow = attn_mask + (size_t)t * T_LEN;
    const float* brow = attn_bias + ((size_t)bh * T_LEN + t) * T_LEN;
    const int* kpr = kpm + b * T_LEN;

    // Q B-fragments: loop-invariant, straight from global
    f16x8 bq[2];
    bq[0] = *(const f16x8*)(Qb + (size_t)t * 64 + quad * 8);
    bq[1] = *(const f16x8*)(Qb + (size_t)t * 64 + 32 + quad * 8);

    float m_i = -1e30f, l_i = 0.0f;
    f32x4 O[4];
#pragma unroll
    for (int dt = 0; dt < 4; ++dt) O[dt] = (f32x4){0.f, 0.f, 0.f, 0.f};

    for (int s0 = 0; s0 < T_LEN; s0 += 64) {
        // S^T tile: rows s (64), cols t (16, this wave's band)
        f32x4 sacc[4];
#pragma unroll
        for (int st = 0; st < 4; ++st) sacc[st] = (f32x4){0.f, 0.f, 0.f, 0.f};
#pragma unroll
        for (int ks = 0; ks < 2; ++ks)
#pragma unroll
            for (int st = 0; st < 4; ++st) {
                const f16x8 ak = *(const f16x8*)(Kb + (size_t)(s0 + st * 16 + lq) * 64 + ks * 32 + quad * 8);
                sacc[st] = __builtin_amdgcn_mfma_f32_16x16x32_f16(ak, bq[ks], sacc[st], 0, 0, 0);
            }

        // mask/bias/kpm: per thread 4 consecutive s -> float4/int4 loads
        float4 m4[4], b4[4]; int4 kp4[4];
#pragma unroll
        for (int st = 0; st < 4; ++st) {
            const int sb = s0 + st * 16 + quad * 4;
            m4[st] = *(const float4*)(mrow + sb);
            b4[st] = *(const float4*)(brow + sb);
            kp4[st] = *(const int4*)(kpr + sb);
        }

        float sv[4][4];
        float rm = -1e30f;
#pragma unroll
        for (int st = 0; st < 4; ++st) {
            const float mv[4] = {m4[st].x, m4[st].y, m4[st].z, m4[st].w};
            const float bv[4] = {b4[st].x, b4[st].y, b4[st].z, b4[st].w};
            const int kv[4] = {kp4[st].x, kp4[st].y, kp4[st].z, kp4[st].w};
#pragma unroll
            for (int r = 0; r < 4; ++r) {
                const float x = sacc[st][r] * 0.125f + mv[r] + bv[r];
                sv[st][r] = kv[r] ? -1e30f : x;
                rm = fmaxf(rm, sv[st][r]);
            }
        }
        // row-max over the 4 quads holding this t
        rm = fmaxf(rm, __shfl_xor(rm, 16));
        rm = fmaxf(rm, __shfl_xor(rm, 32));
        const float mn = fmaxf(m_i, rm);
        const float alpha = __expf(m_i - mn);
        m_i = mn;

        __builtin_amdgcn_wave_barrier();   // prev-tile P reads precede overwrite
        float rs = 0.0f;
#pragma unroll
        for (int st = 0; st < 4; ++st) {
            f16x4 pv;
#pragma unroll
            for (int r = 0; r < 4; ++r) {
                const float p = __expf(sv[st][r] - mn);
                rs += p;
                pv[r] = (f16)p;
            }
            *(f16x4*)&Pw[lq * LDP + st * 16 + quad * 4] = pv;
        }
        rs += __shfl_xor(rs, 16);
        rs += __shfl_xor(rs, 32);
        l_i = l_i * alpha + rs;

        // broadcast alpha (per t=lq) to O rows (t=quad*4+r)
        float aB[4];
#pragma unroll
        for (int r = 0; r < 4; ++r) aB[r] = __shfl(alpha, quad * 4 + r, 16);
#pragma unroll
        for (int dt = 0; dt < 4; ++dt)
#pragma unroll
            for (int r = 0; r < 4; ++r) O[dt][r] *= aB[r];

        __builtin_amdgcn_wave_barrier();   // P writes precede P reads (DS in-order per wave)

        // O += P V  (A = P band, B = V^T fragments straight from global)
#pragma unroll
        for (int ks = 0; ks < 2; ++ks) {
            const f16x8 ap = *(const f16x8*)&Pw[lq * LDP + ks * 32 + quad * 8];
#pragma unroll
            for (int dt = 0; dt < 4; ++dt) {
                const f16x8 av = *(const f16x8*)(Vb + (size_t)(dt * 16 + lq) * 1024 + s0 + ks * 32 + quad * 8);
                O[dt] = __builtin_amdgcn_mfma_f32_16x16x32_f16(ap, av, O[dt], 0, 0, 0);
            }
        }
    }

    // epilogue: normalize by l (broadcast per O-row), write ctx f16 [t*4+b][e]
    float lB[4];
#pragma unroll
    for (int r = 0; r < 4; ++r) lB[r] = __shfl(l_i, quad * 4 + r, 16);
#pragma unroll
    for (int r = 0; r < 4; ++r) {
        const float inv = 1.0f / lB[r];
        const int tt = q0 + wv * 16 + quad * 4 + r;
#pragma unroll
        for (int dt = 0; dt < 4; ++dt)
            ctx[((size_t)tt * B_SZ + b) * EMB + hh * HD + dt * 16 + lq] = (f16)(O[dt][r] * inv);
    }
}

// ---------------------------------------------------------------------------
extern "C" void kernel_launch(void* const* d_in, const int* in_sizes, int n_in,
                              void* d_out, int out_size, void* d_ws, size_t ws_size,
                              hipStream_t stream)
{
    const float* query     = (const float*)d_in[0];
    const int*   kpm       = (const int*)  d_in[1];
    const float* attn_mask = (const float*)d_in[2];
    const float* attn_bias = (const float*)d_in[3];
    const float* W_in      = (const float*)d_in[4];
    const float* b_in      = (const float*)d_in[5];
    const float* W_out     = (const float*)d_in[6];
    const float* b_out     = (const float*)d_in[7];
    float* out = (float*)d_out;

    // workspace (f16): 25.2M halves = 50.4 MB
    f16* q16    = (f16*)d_ws;                                   // 4096x1024
    f16* win16  = q16    + (size_t)4096 * 1024;                 // 3072x1024
    f16* wout16 = win16  + (size_t)3072 * 1024;                 // 1024x1024
    f16* Qh     = wout16 + (size_t)1024 * 1024;                 // 64 x 1024 x 64
    f16* Kh     = Qh     + (size_t)64 * 65536;
    f16* Vth    = Kh     + (size_t)64 * 65536;                  // 64 x 64 x 1024
    f16* ctx16  = Vth    + (size_t)64 * 65536;                  // 4096x1024

    cvt_f32_to_f16<<<4096 * 1024 / 1024, 256, 0, stream>>>(query, q16,    4096 * 1024 / 4);
    cvt_f32_to_f16<<<3072 * 1024 / 1024, 256, 0, stream>>>(W_in,  win16,  3072 * 1024 / 4);
    cvt_f32_to_f16<<<1024 * 1024 / 1024, 256, 0, stream>>>(W_out, wout16, 1024 * 1024 / 4);

    // K1: qkv = q16 * win16^T + b_in, scattered to per-head Qh/Kh/Vth
    dim3 g1(4096 / 128, 3072 / 128);
    gemm_f16_v2<2><<<g1, 256, 0, stream>>>(q16, win16, b_in, nullptr,
                                           Qh, Kh, Vth, 4096, 3072, 1024);

    // K2: fused attention -> ctx16
    dim3 g2(T_LEN / 64, B_SZ * NH);
    attn_v2<<<g2, 256, 0, stream>>>(Qh, Kh, Vth, kpm, attn_mask, attn_bias, ctx16);

    // K3: out = ctx16 * wout16^T + b_out (f32)
    dim3 g3(4096 / 128, 1024 / 128);
    gemm_f16_v2<0><<<g3, 256, 0, stream>>>(ctx16, wout16, b_out, out,
                                           nullptr, nullptr, nullptr, 4096, 1024, 1024);
}

// Round 4
// 590.541 us; speedup vs baseline: 1.8266x; 1.0011x over previous
//
#include <hip/hip_runtime.h>

#define T_LEN 1024
#define B_SZ 4
#define EMB 1024
#define NH 16
#define HD 64
#define QKV_LD 3072

typedef _Float16 f16;
typedef __attribute__((ext_vector_type(8))) _Float16 f16x8;
typedef __attribute__((ext_vector_type(4))) _Float16 f16x4;
typedef __attribute__((ext_vector_type(4))) float f32x4;

// async global->LDS, 16B per lane. LDS dest must be wave-uniform base + lane*16.
__device__ __forceinline__ void gload16(const f16* g, f16* l) {
    __builtin_amdgcn_global_load_lds(
        (const __attribute__((address_space(1))) void*)g,
        (__attribute__((address_space(3))) void*)l, 16, 0, 0);
}

// ---------------------------------------------------------------------------
__global__ __launch_bounds__(256) void cvt_f32_to_f16(
    const float* __restrict__ in, f16* __restrict__ out, int n4)
{
    int i = blockIdx.x * 256 + threadIdx.x;
    if (i < n4) {
        float4 v = ((const float4*)in)[i];
        f16x4 h = { (f16)v.x, (f16)v.y, (f16)v.z, (f16)v.w };
        ((f16x4*)out)[i] = h;
    }
}

// ---------------------------------------------------------------------------
// Transposed f16 MFMA GEMM: Out[x][e] = sum_k Wt[e][k]*Xa[x][k] + bias[e].
// m-dim = e (weight rows), n-dim = x (activation rows) -> the per-thread
// 4-reg accumulator dimension is CONTIGUOUS in e: dense f16x4/float4 stores.
// 128x128 tile, BK=32, m97-style global_load_lds staging, unpadded [128][32].
// ---------------------------------------------------------------------------
template<bool OUT_HALF>
__global__ __launch_bounds__(256) void gemm_ct(
    const f16* __restrict__ Wt, const f16* __restrict__ Xa,
    const float* __restrict__ bias, void* __restrict__ Out,
    int K, int ldo)
{
    __shared__ f16 As[128 * 32];   // e-tile
    __shared__ f16 Bs[128 * 32];   // x-tile
    const int tid = threadIdx.x;
    const int wv = tid >> 6, lane = tid & 63;
    const int lq = lane & 15, quad = lane >> 4;
    const int m0 = blockIdx.x * 128, n0 = blockIdx.y * 128;
    const int wm = (wv >> 1) * 64, wn = (wv & 1) * 64;

    const int s1 = tid, s2 = 256 + tid;
    const f16* a1 = Wt + (size_t)(m0 + (s1 >> 2)) * K + (s1 & 3) * 8;
    const f16* a2 = Wt + (size_t)(m0 + (s2 >> 2)) * K + (s2 & 3) * 8;
    const f16* b1 = Xa + (size_t)(n0 + (s1 >> 2)) * K + (s1 & 3) * 8;
    const f16* b2 = Xa + (size_t)(n0 + (s2 >> 2)) * K + (s2 & 3) * 8;
    f16* lA1 = As + s1 * 8; f16* lA2 = As + s2 * 8;
    f16* lB1 = Bs + s1 * 8; f16* lB2 = Bs + s2 * 8;

    f32x4 acc[4][4];
#pragma unroll
    for (int i = 0; i < 4; ++i)
#pragma unroll
        for (int j = 0; j < 4; ++j) acc[i][j] = (f32x4){0.f, 0.f, 0.f, 0.f};

    for (int k0 = 0; k0 < K; k0 += 32) {
        __syncthreads();
        gload16(a1 + k0, lA1);
        gload16(a2 + k0, lA2);
        gload16(b1 + k0, lB1);
        gload16(b2 + k0, lB2);
        __syncthreads();
        f16x8 af[4], bf[4];
#pragma unroll
        for (int t = 0; t < 4; ++t) {
            af[t] = *(const f16x8*)&As[(wm + t * 16 + lq) * 32 + quad * 8];
            bf[t] = *(const f16x8*)&Bs[(wn + t * 16 + lq) * 32 + quad * 8];
        }
#pragma unroll
        for (int mt = 0; mt < 4; ++mt)
#pragma unroll
            for (int nt = 0; nt < 4; ++nt)
                acc[mt][nt] = __builtin_amdgcn_mfma_f32_16x16x32_f16(
                    af[mt], bf[nt], acc[mt][nt], 0, 0, 0);
    }

    // epilogue: C/D col = lq = x-row, row = quad*4+r = e (contiguous per thread)
#pragma unroll
    for (int mt = 0; mt < 4; ++mt) {
        const int e0 = m0 + wm + mt * 16 + quad * 4;
        const float4 bb = *(const float4*)(bias + e0);
#pragma unroll
        for (int nt = 0; nt < 4; ++nt) {
            const int xr = n0 + wn + nt * 16 + lq;
            if (OUT_HALF) {
                f16x4 h = { (f16)(acc[mt][nt][0] + bb.x), (f16)(acc[mt][nt][1] + bb.y),
                            (f16)(acc[mt][nt][2] + bb.z), (f16)(acc[mt][nt][3] + bb.w) };
                *(f16x4*)((f16*)Out + (size_t)xr * ldo + e0) = h;
            } else {
                float4 o = { acc[mt][nt][0] + bb.x, acc[mt][nt][1] + bb.y,
                             acc[mt][nt][2] + bb.z, acc[mt][nt][3] + bb.w };
                *(float4*)((float*)Out + (size_t)xr * ldo + e0) = o;
            }
        }
    }
}

// ---------------------------------------------------------------------------
// V transpose: qkv natural v-section -> Vth[bh][d][t]. LDS-tiled, coalesced
// global reads AND writes. Block = (bh, 256-t chunk), 256 threads.
// ---------------------------------------------------------------------------
__global__ __launch_bounds__(256) void vtrans(
    const f16* __restrict__ qkv, f16* __restrict__ Vth)
{
    __shared__ f16 Ls[256 * 66];
    const int bh = blockIdx.x;
    const int t0 = blockIdx.y * 256;
    const int b = bh >> 4, hh = bh & 15;
    const int tid = threadIdx.x;

#pragma unroll
    for (int p = 0; p < 8; ++p) {
        const int g = p * 2048 + tid * 8;
        const int ti = g >> 6, dj = g & 63;
        f16x8 v = *(const f16x8*)(qkv + (size_t)((t0 + ti) * 4 + b) * QKV_LD + 2048 + hh * 64 + dj);
        *(f16x8*)&Ls[ti * 66 + dj] = v;
    }
    __syncthreads();
#pragma unroll
    for (int p = 0; p < 8; ++p) {
        const int g = p * 2048 + tid * 8;
        const int d = g >> 8, tt = g & 255;
        f16x8 o;
#pragma unroll
        for (int j = 0; j < 8; ++j) o[j] = Ls[(tt + j) * 66 + d];
        *(f16x8*)(Vth + (size_t)bh * 65536 + (size_t)d * 1024 + t0 + tt) = o;
    }
}

// ---------------------------------------------------------------------------
// Fused flash attention v3. Block = 64 q-rows of one bh, 4 waves, barrier-free.
// S^T per tile (A=K, B=Q -> C col=t, row=s). Loads issued in CONSUMPTION
// ORDER (vmcnt retires in-order): K, V, mask, kpm, then NEXT-tile bias
// (register prefetch, ~full iteration in flight). LDS only for wave-private P.
// ---------------------------------------------------------------------------
__global__ __launch_bounds__(256) void attn_v3(
    const f16* __restrict__ qkv, const f16* __restrict__ Vth,
    const int* __restrict__ kpm, const float* __restrict__ attn_mask,
    const float* __restrict__ attn_bias, f16* __restrict__ ctx)
{
    const int LDP = 72;
    __shared__ f16 Ps[4 * 16 * LDP];

    const int tid = threadIdx.x;
    const int wv = tid >> 6, lane = tid & 63;
    const int lq = lane & 15, quad = lane >> 4;
    const int q0 = blockIdx.x * 64;
    const int bh = blockIdx.y;
    const int b = bh >> 4, hh = bh & 15;
    f16* Pw = Ps + wv * 16 * LDP;

    const int t = q0 + wv * 16 + lq;
    const float* mrow = attn_mask + (size_t)t * T_LEN;
    const float* brow = attn_bias + ((size_t)bh * T_LEN + t) * T_LEN;
    const int* kpr = kpm + b * T_LEN;
    const f16* Vb = Vth + (size_t)bh * 65536;

    // loop-invariant Q B-fragments
    f16x8 bq[2];
    {
        const f16* qrow = qkv + (size_t)(t * 4 + b) * QKV_LD + hh * 64;
        bq[0] = *(const f16x8*)(qrow + quad * 8);
        bq[1] = *(const f16x8*)(qrow + 32 + quad * 8);
    }

    float m_i = -1e30f, l_i = 0.0f;
    f32x4 O[4];
#pragma unroll
    for (int dt = 0; dt < 4; ++dt) O[dt] = (f32x4){0.f, 0.f, 0.f, 0.f};

    // prefetch bias for tile 0
    float4 b4[4];
#pragma unroll
    for (int st = 0; st < 4; ++st)
        b4[st] = *(const float4*)(brow + st * 16 + quad * 4);

    for (int s0 = 0; s0 < T_LEN; s0 += 64) {
        // ---- issue loads in consumption order ----
        // (1) K fragments (consumed first, by MFMA)
        f16x8 ak[2][4];
#pragma unroll
        for (int ks = 0; ks < 2; ++ks)
#pragma unroll
            for (int st = 0; st < 4; ++st)
                ak[ks][st] = *(const f16x8*)(qkv
                    + (size_t)((s0 + st * 16 + lq) * 4 + b) * QKV_LD
                    + EMB + hh * 64 + ks * 32 + quad * 8);
        // (2) V fragments (consumed at PV, end of tile)
        f16x8 av[2][4];
#pragma unroll
        for (int ks = 0; ks < 2; ++ks)
#pragma unroll
            for (int dt = 0; dt < 4; ++dt)
                av[ks][dt] = *(const f16x8*)(Vb + (size_t)(dt * 16 + lq) * 1024
                                             + s0 + ks * 32 + quad * 8);
        // (3) mask + kpm for THIS tile (L2/L3-hot; consumed at softmax)
        float4 m4[4]; int4 kp4[4];
#pragma unroll
        for (int st = 0; st < 4; ++st) {
            const int sb = s0 + st * 16 + quad * 4;
            m4[st] = *(const float4*)(mrow + sb);
            kp4[st] = *(const int4*)(kpr + sb);
        }
        // (4) bias for NEXT tile (HBM-cold; youngest -> stays in flight)
        float4 b4n[4];
        if (s0 + 64 < T_LEN) {
#pragma unroll
            for (int st = 0; st < 4; ++st)
                b4n[st] = *(const float4*)(brow + s0 + 64 + st * 16 + quad * 4);
        }

        // ---- S^T = K Q^T ----
        f32x4 sacc[4];
#pragma unroll
        for (int st = 0; st < 4; ++st) sacc[st] = (f32x4){0.f, 0.f, 0.f, 0.f};
#pragma unroll
        for (int ks = 0; ks < 2; ++ks)
#pragma unroll
            for (int st = 0; st < 4; ++st)
                sacc[st] = __builtin_amdgcn_mfma_f32_16x16x32_f16(
                    ak[ks][st], bq[ks], sacc[st], 0, 0, 0);

        // ---- scale + mask + bias + kpm ----
        float sv[4][4];
        float rm = -1e30f;
#pragma unroll
        for (int st = 0; st < 4; ++st) {
            const float mv[4] = {m4[st].x, m4[st].y, m4[st].z, m4[st].w};
            const float bv[4] = {b4[st].x, b4[st].y, b4[st].z, b4[st].w};
            const int kv[4] = {kp4[st].x, kp4[st].y, kp4[st].z, kp4[st].w};
#pragma unroll
            for (int r = 0; r < 4; ++r) {
                const float x = sacc[st][r] * 0.125f + mv[r] + bv[r];
                sv[st][r] = kv[r] ? -1e30f : x;
                rm = fmaxf(rm, sv[st][r]);
            }
        }
        rm = fmaxf(rm, __shfl_xor(rm, 16));
        rm = fmaxf(rm, __shfl_xor(rm, 32));
        const float mn = fmaxf(m_i, rm);
        const float alpha = __expf(m_i - mn);
        m_i = mn;

        __builtin_amdgcn_wave_barrier();   // prev-tile P reads precede overwrite
        float rs = 0.0f;
#pragma unroll
        for (int st = 0; st < 4; ++st) {
            f16x4 pv;
#pragma unroll
            for (int r = 0; r < 4; ++r) {
                const float p = __expf(sv[st][r] - mn);
                rs += p;
                pv[r] = (f16)p;
            }
            *(f16x4*)&Pw[lq * LDP + st * 16 + quad * 4] = pv;
        }
        rs += __shfl_xor(rs, 16);
        rs += __shfl_xor(rs, 32);
        l_i = l_i * alpha + rs;

        float aB[4];
#pragma unroll
        for (int r = 0; r < 4; ++r) aB[r] = __shfl(alpha, quad * 4 + r, 16);
#pragma unroll
        for (int dt = 0; dt < 4; ++dt)
#pragma unroll
            for (int r = 0; r < 4; ++r) O[dt][r] *= aB[r];

        __builtin_amdgcn_wave_barrier();   // P writes precede P reads

        // ---- O += P V ----
#pragma unroll
        for (int ks = 0; ks < 2; ++ks) {
            const f16x8 ap = *(const f16x8*)&Pw[lq * LDP + ks * 32 + quad * 8];
#pragma unroll
            for (int dt = 0; dt < 4; ++dt)
                O[dt] = __builtin_amdgcn_mfma_f32_16x16x32_f16(
                    ap, av[ks][dt], O[dt], 0, 0, 0);
        }

        // rotate bias prefetch
#pragma unroll
        for (int st = 0; st < 4; ++st) b4[st] = b4n[st];
    }

    // epilogue
    float lB[4];
#pragma unroll
    for (int r = 0; r < 4; ++r) lB[r] = __shfl(l_i, quad * 4 + r, 16);
#pragma unroll
    for (int r = 0; r < 4; ++r) {
        const float inv = 1.0f / lB[r];
        const int tt = q0 + wv * 16 + quad * 4 + r;
#pragma unroll
        for (int dt = 0; dt < 4; ++dt)
            ctx[((size_t)tt * B_SZ + b) * EMB + hh * HD + dt * 16 + lq] = (f16)(O[dt][r] * inv);
    }
}

// ---------------------------------------------------------------------------
extern "C" void kernel_launch(void* const* d_in, const int* in_sizes, int n_in,
                              void* d_out, int out_size, void* d_ws, size_t ws_size,
                              hipStream_t stream)
{
    const float* query     = (const float*)d_in[0];
    const int*   kpm       = (const int*)  d_in[1];
    const float* attn_mask = (const float*)d_in[2];
    const float* attn_bias = (const float*)d_in[3];
    const float* W_in      = (const float*)d_in[4];
    const float* b_in      = (const float*)d_in[5];
    const float* W_out     = (const float*)d_in[6];
    const float* b_out     = (const float*)d_in[7];
    float* out = (float*)d_out;

    // workspace (f16): 28M halves = 56 MB
    f16* q16    = (f16*)d_ws;                                   // 4096x1024
    f16* win16  = q16    + (size_t)4096 * 1024;                 // 3072x1024
    f16* wout16 = win16  + (size_t)3072 * 1024;                 // 1024x1024
    f16* qkv16  = wout16 + (size_t)1024 * 1024;                 // 4096x3072 natural
    f16* Vth    = qkv16  + (size_t)4096 * 3072;                 // 64 x 64 x 1024
    f16* ctx16  = Vth    + (size_t)64 * 65536;                  // 4096x1024

    cvt_f32_to_f16<<<4096 * 1024 / 1024, 256, 0, stream>>>(query, q16,    4096 * 1024 / 4);
    cvt_f32_to_f16<<<3072 * 1024 / 1024, 256, 0, stream>>>(W_in,  win16,  3072 * 1024 / 4);
    cvt_f32_to_f16<<<1024 * 1024 / 1024, 256, 0, stream>>>(W_out, wout16, 1024 * 1024 / 4);

    // K1: qkv[x][e] = q16 * W_in^T + b_in   (E=3072, X=4096, K=1024)
    dim3 g1(3072 / 128, 4096 / 128);
    gemm_ct<true><<<g1, 256, 0, stream>>>(win16, q16, b_in, qkv16, 1024, QKV_LD);

    // V transpose -> Vth[bh][d][t]
    dim3 gv(64, 4);
    vtrans<<<gv, 256, 0, stream>>>(qkv16, Vth);

    // K2: fused attention -> ctx16
    dim3 g2(T_LEN / 64, B_SZ * NH);
    attn_v3<<<g2, 256, 0, stream>>>(qkv16, Vth, kpm, attn_mask, attn_bias, ctx16);

    // K3: out[x][e] = ctx16 * W_out^T + b_out (E=1024, X=4096, K=1024, f32)
    dim3 g3(1024 / 128, 4096 / 128);
    gemm_ct<false><<<g3, 256, 0, stream>>>(wout16, ctx16, b_out, out, 1024, 1024);
}

// Round 5
// 586.592 us; speedup vs baseline: 1.8389x; 1.0067x over previous
//
#include <hip/hip_runtime.h>

#define T_LEN 1024
#define B_SZ 4
#define EMB 1024
#define NH 16
#define HD 64
#define QKV_LD 3072

typedef _Float16 f16;
typedef __attribute__((ext_vector_type(8))) _Float16 f16x8;
typedef __attribute__((ext_vector_type(4))) _Float16 f16x4;
typedef __attribute__((ext_vector_type(4))) float f32x4;

// async global->LDS, 16B per lane. LDS dest must be wave-uniform base + lane*16.
__device__ __forceinline__ void gload16(const f16* g, f16* l) {
    __builtin_amdgcn_global_load_lds(
        (const __attribute__((address_space(1))) void*)g,
        (__attribute__((address_space(3))) void*)l, 16, 0, 0);
}

// ---------------------------------------------------------------------------
// fused fp32->fp16 conversion for query / W_in / W_out (one launch)
// ---------------------------------------------------------------------------
#define N4_Q  (4096 * 1024 / 4)
#define N4_WI (3072 * 1024 / 4)
#define N4_WO (1024 * 1024 / 4)
__global__ __launch_bounds__(256) void cvt_all(
    const float* __restrict__ q, const float* __restrict__ wi,
    const float* __restrict__ wo, f16* __restrict__ q16,
    f16* __restrict__ wi16, f16* __restrict__ wo16)
{
    int i = blockIdx.x * 256 + threadIdx.x;
    const float* src; f16* dst; int off;
    if (i < N4_Q)             { src = q;  dst = q16;  off = i; }
    else if (i < N4_Q + N4_WI){ src = wi; dst = wi16; off = i - N4_Q; }
    else                      { src = wo; dst = wo16; off = i - N4_Q - N4_WI; }
    float4 v = ((const float4*)src)[off];
    f16x4 h = { (f16)v.x, (f16)v.y, (f16)v.z, (f16)v.w };
    ((f16x4*)dst)[off] = h;
}

// ---------------------------------------------------------------------------
// Transposed f16 MFMA GEMM: Out[x][e] = sum_k Wt[e][k]*Xa[x][k] + bias[e].
// 128x128 tile, BK=32, m97-style global_load_lds staging, unpadded [128][32].
// (unchanged from R4 — control variable; counters next round attribute its cost)
// ---------------------------------------------------------------------------
template<bool OUT_HALF>
__global__ __launch_bounds__(256) void gemm_ct(
    const f16* __restrict__ Wt, const f16* __restrict__ Xa,
    const float* __restrict__ bias, void* __restrict__ Out,
    int K, int ldo)
{
    __shared__ f16 As[128 * 32];
    __shared__ f16 Bs[128 * 32];
    const int tid = threadIdx.x;
    const int wv = tid >> 6, lane = tid & 63;
    const int lq = lane & 15, quad = lane >> 4;
    const int m0 = blockIdx.x * 128, n0 = blockIdx.y * 128;
    const int wm = (wv >> 1) * 64, wn = (wv & 1) * 64;

    const int s1 = tid, s2 = 256 + tid;
    const f16* a1 = Wt + (size_t)(m0 + (s1 >> 2)) * K + (s1 & 3) * 8;
    const f16* a2 = Wt + (size_t)(m0 + (s2 >> 2)) * K + (s2 & 3) * 8;
    const f16* b1 = Xa + (size_t)(n0 + (s1 >> 2)) * K + (s1 & 3) * 8;
    const f16* b2 = Xa + (size_t)(n0 + (s2 >> 2)) * K + (s2 & 3) * 8;
    f16* lA1 = As + s1 * 8; f16* lA2 = As + s2 * 8;
    f16* lB1 = Bs + s1 * 8; f16* lB2 = Bs + s2 * 8;

    f32x4 acc[4][4];
#pragma unroll
    for (int i = 0; i < 4; ++i)
#pragma unroll
        for (int j = 0; j < 4; ++j) acc[i][j] = (f32x4){0.f, 0.f, 0.f, 0.f};

    for (int k0 = 0; k0 < K; k0 += 32) {
        __syncthreads();
        gload16(a1 + k0, lA1);
        gload16(a2 + k0, lA2);
        gload16(b1 + k0, lB1);
        gload16(b2 + k0, lB2);
        __syncthreads();
        f16x8 af[4], bf[4];
#pragma unroll
        for (int t = 0; t < 4; ++t) {
            af[t] = *(const f16x8*)&As[(wm + t * 16 + lq) * 32 + quad * 8];
            bf[t] = *(const f16x8*)&Bs[(wn + t * 16 + lq) * 32 + quad * 8];
        }
#pragma unroll
        for (int mt = 0; mt < 4; ++mt)
#pragma unroll
            for (int nt = 0; nt < 4; ++nt)
                acc[mt][nt] = __builtin_amdgcn_mfma_f32_16x16x32_f16(
                    af[mt], bf[nt], acc[mt][nt], 0, 0, 0);
    }

#pragma unroll
    for (int mt = 0; mt < 4; ++mt) {
        const int e0 = m0 + wm + mt * 16 + quad * 4;
        const float4 bb = *(const float4*)(bias + e0);
#pragma unroll
        for (int nt = 0; nt < 4; ++nt) {
            const int xr = n0 + wn + nt * 16 + lq;
            if (OUT_HALF) {
                f16x4 h = { (f16)(acc[mt][nt][0] + bb.x), (f16)(acc[mt][nt][1] + bb.y),
                            (f16)(acc[mt][nt][2] + bb.z), (f16)(acc[mt][nt][3] + bb.w) };
                *(f16x4*)((f16*)Out + (size_t)xr * ldo + e0) = h;
            } else {
                float4 o = { acc[mt][nt][0] + bb.x, acc[mt][nt][1] + bb.y,
                             acc[mt][nt][2] + bb.z, acc[mt][nt][3] + bb.w };
                *(float4*)((float*)Out + (size_t)xr * ldo + e0) = o;
            }
        }
    }
}

// ---------------------------------------------------------------------------
// V transpose: qkv natural v-section -> Vth[bh][d][t].
// ---------------------------------------------------------------------------
__global__ __launch_bounds__(256) void vtrans(
    const f16* __restrict__ qkv, f16* __restrict__ Vth)
{
    __shared__ f16 Ls[256 * 66];
    const int bh = blockIdx.x;
    const int t0 = blockIdx.y * 256;
    const int b = bh >> 4, hh = bh & 15;
    const int tid = threadIdx.x;

#pragma unroll
    for (int p = 0; p < 8; ++p) {
        const int g = p * 2048 + tid * 8;
        const int ti = g >> 6, dj = g & 63;
        f16x8 v = *(const f16x8*)(qkv + (size_t)((t0 + ti) * 4 + b) * QKV_LD + 2048 + hh * 64 + dj);
        *(f16x8*)&Ls[ti * 66 + dj] = v;
    }
    __syncthreads();
#pragma unroll
    for (int p = 0; p < 8; ++p) {
        const int g = p * 2048 + tid * 8;
        const int d = g >> 8, tt = g & 255;
        f16x8 o;
#pragma unroll
        for (int j = 0; j < 8; ++j) o[j] = Ls[(tt + j) * 66 + d];
        *(f16x8*)(Vth + (size_t)bh * 65536 + (size_t)d * 1024 + t0 + tt) = o;
    }
}

// ---------------------------------------------------------------------------
// Fused flash attention v4. Block = 64 q-rows of one bh, 4 waves, barrier-free.
// Outer loop 128 keys; bias for the NEXT 128-block prefetched as one burst of
// 8 row-contiguous nontemporal instructions (512 B/row page locality, no L2
// pollution). K/V/mask/kpm JIT per 64-subtile (L2-hot). Wave-private P LDS.
// ---------------------------------------------------------------------------
__global__ __launch_bounds__(256) void attn_v4(
    const f16* __restrict__ qkv, const f16* __restrict__ Vth,
    const int* __restrict__ kpm, const float* __restrict__ attn_mask,
    const float* __restrict__ attn_bias, f16* __restrict__ ctx)
{
    const int LDP = 72;
    __shared__ f16 Ps[4 * 16 * LDP];

    const int tid = threadIdx.x;
    const int wv = tid >> 6, lane = tid & 63;
    const int lq = lane & 15, quad = lane >> 4;
    const int q0 = blockIdx.x * 64;
    const int bh = blockIdx.y;
    const int b = bh >> 4, hh = bh & 15;
    f16* Pw = Ps + wv * 16 * LDP;

    const int t = q0 + wv * 16 + lq;
    const float* mrow = attn_mask + (size_t)t * T_LEN;
    const float* brow = attn_bias + ((size_t)bh * T_LEN + t) * T_LEN;
    const int* kpr = kpm + b * T_LEN;
    const f16* Vb = Vth + (size_t)bh * 65536;

    f16x8 bq[2];
    {
        const f16* qrow = qkv + (size_t)(t * 4 + b) * QKV_LD + hh * 64;
        bq[0] = *(const f16x8*)(qrow + quad * 8);
        bq[1] = *(const f16x8*)(qrow + 32 + quad * 8);
    }

    float m_i = -1e30f, l_i = 0.0f;
    f32x4 O[4];
#pragma unroll
    for (int dt = 0; dt < 4; ++dt) O[dt] = (f32x4){0.f, 0.f, 0.f, 0.f};

    // bias burst for the first 128-block: 8 row-contiguous nt loads
    f32x4 bb[8];
#pragma unroll
    for (int j = 0; j < 8; ++j)
        bb[j] = __builtin_nontemporal_load((const f32x4*)(brow + j * 16 + quad * 4));

    for (int s0 = 0; s0 < T_LEN; s0 += 128) {
        f32x4 bbn[8];
#pragma unroll
        for (int half = 0; half < 2; ++half) {
            const int sh = s0 + half * 64;

            // (1) K fragments (consumed first)
            f16x8 ak[2][4];
#pragma unroll
            for (int ks = 0; ks < 2; ++ks)
#pragma unroll
                for (int st = 0; st < 4; ++st)
                    ak[ks][st] = *(const f16x8*)(qkv
                        + (size_t)((sh + st * 16 + lq) * 4 + b) * QKV_LD
                        + EMB + hh * 64 + ks * 32 + quad * 8);
            // (2) V fragments (consumed at PV)
            f16x8 av[2][4];
#pragma unroll
            for (int ks = 0; ks < 2; ++ks)
#pragma unroll
                for (int dt = 0; dt < 4; ++dt)
                    av[ks][dt] = *(const f16x8*)(Vb + (size_t)(dt * 16 + lq) * 1024
                                                 + sh + ks * 32 + quad * 8);
            // (3) mask + kpm (L2/L3-hot)
            f32x4 m4[4]; int4 kp4[4];
#pragma unroll
            for (int st = 0; st < 4; ++st) {
                const int sb = sh + st * 16 + quad * 4;
                m4[st] = *(const f32x4*)(mrow + sb);
                kp4[st] = *(const int4*)(kpr + sb);
            }
            // (4) half==1: burst-prefetch bias for next 128-block (youngest)
            if (half == 1 && s0 + 128 < T_LEN) {
#pragma unroll
                for (int j = 0; j < 8; ++j)
                    bbn[j] = __builtin_nontemporal_load(
                        (const f32x4*)(brow + s0 + 128 + j * 16 + quad * 4));
            }

            // ---- S^T = K Q^T ----
            f32x4 sacc[4];
#pragma unroll
            for (int st = 0; st < 4; ++st) sacc[st] = (f32x4){0.f, 0.f, 0.f, 0.f};
#pragma unroll
            for (int ks = 0; ks < 2; ++ks)
#pragma unroll
                for (int st = 0; st < 4; ++st)
                    sacc[st] = __builtin_amdgcn_mfma_f32_16x16x32_f16(
                        ak[ks][st], bq[ks], sacc[st], 0, 0, 0);

            // ---- scale + mask + bias + kpm ----
            float sv[4][4];
            float rm = -1e30f;
#pragma unroll
            for (int st = 0; st < 4; ++st) {
                const f32x4 bv = bb[half * 4 + st];
                const int kv[4] = {kp4[st].x, kp4[st].y, kp4[st].z, kp4[st].w};
#pragma unroll
                for (int r = 0; r < 4; ++r) {
                    const float x = sacc[st][r] * 0.125f + m4[st][r] + bv[r];
                    sv[st][r] = kv[r] ? -1e30f : x;
                    rm = fmaxf(rm, sv[st][r]);
                }
            }
            rm = fmaxf(rm, __shfl_xor(rm, 16));
            rm = fmaxf(rm, __shfl_xor(rm, 32));
            const float mn = fmaxf(m_i, rm);
            const float alpha = __expf(m_i - mn);
            m_i = mn;

            __builtin_amdgcn_wave_barrier();   // prev P reads precede overwrite
            float rs = 0.0f;
#pragma unroll
            for (int st = 0; st < 4; ++st) {
                f16x4 pv;
#pragma unroll
                for (int r = 0; r < 4; ++r) {
                    const float p = __expf(sv[st][r] - mn);
                    rs += p;
                    pv[r] = (f16)p;
                }
                *(f16x4*)&Pw[lq * LDP + st * 16 + quad * 4] = pv;
            }
            rs += __shfl_xor(rs, 16);
            rs += __shfl_xor(rs, 32);
            l_i = l_i * alpha + rs;

            float aB[4];
#pragma unroll
            for (int r = 0; r < 4; ++r) aB[r] = __shfl(alpha, quad * 4 + r, 16);
#pragma unroll
            for (int dt = 0; dt < 4; ++dt)
#pragma unroll
                for (int r = 0; r < 4; ++r) O[dt][r] *= aB[r];

            __builtin_amdgcn_wave_barrier();   // P writes precede P reads

            // ---- O += P V ----
#pragma unroll
            for (int ks = 0; ks < 2; ++ks) {
                const f16x8 ap = *(const f16x8*)&Pw[lq * LDP + ks * 32 + quad * 8];
#pragma unroll
                for (int dt = 0; dt < 4; ++dt)
                    O[dt] = __builtin_amdgcn_mfma_f32_16x16x32_f16(
                        ap, av[ks][dt], O[dt], 0, 0, 0);
            }
        }
#pragma unroll
        for (int j = 0; j < 8; ++j) bb[j] = bbn[j];
    }

    // epilogue
    float lB[4];
#pragma unroll
    for (int r = 0; r < 4; ++r) lB[r] = __shfl(l_i, quad * 4 + r, 16);
#pragma unroll
    for (int r = 0; r < 4; ++r) {
        const float inv = 1.0f / lB[r];
        const int tt = q0 + wv * 16 + quad * 4 + r;
#pragma unroll
        for (int dt = 0; dt < 4; ++dt)
            ctx[((size_t)tt * B_SZ + b) * EMB + hh * HD + dt * 16 + lq] = (f16)(O[dt][r] * inv);
    }
}

// ---------------------------------------------------------------------------
extern "C" void kernel_launch(void* const* d_in, const int* in_sizes, int n_in,
                              void* d_out, int out_size, void* d_ws, size_t ws_size,
                              hipStream_t stream)
{
    const float* query     = (const float*)d_in[0];
    const int*   kpm       = (const int*)  d_in[1];
    const float* attn_mask = (const float*)d_in[2];
    const float* attn_bias = (const float*)d_in[3];
    const float* W_in      = (const float*)d_in[4];
    const float* b_in      = (const float*)d_in[5];
    const float* W_out     = (const float*)d_in[6];
    const float* b_out     = (const float*)d_in[7];
    float* out = (float*)d_out;

    f16* q16    = (f16*)d_ws;                                   // 4096x1024
    f16* win16  = q16    + (size_t)4096 * 1024;                 // 3072x1024
    f16* wout16 = win16  + (size_t)3072 * 1024;                 // 1024x1024
    f16* qkv16  = wout16 + (size_t)1024 * 1024;                 // 4096x3072
    f16* Vth    = qkv16  + (size_t)4096 * 3072;                 // 64 x 64 x 1024
    f16* ctx16  = Vth    + (size_t)64 * 65536;                  // 4096x1024

    cvt_all<<<(N4_Q + N4_WI + N4_WO) / 256, 256, 0, stream>>>(
        query, W_in, W_out, q16, win16, wout16);

    dim3 g1(3072 / 128, 4096 / 128);
    gemm_ct<true><<<g1, 256, 0, stream>>>(win16, q16, b_in, qkv16, 1024, QKV_LD);

    dim3 gv(64, 4);
    vtrans<<<gv, 256, 0, stream>>>(qkv16, Vth);

    dim3 g2(T_LEN / 64, B_SZ * NH);
    attn_v4<<<g2, 256, 0, stream>>>(qkv16, Vth, kpm, attn_mask, attn_bias, ctx16);

    dim3 g3(1024 / 128, 4096 / 128);
    gemm_ct<false><<<g3, 256, 0, stream>>>(wout16, ctx16, b_out, out, 1024, 1024);
}